// Round 1
// baseline (214.974 us; speedup 1.0000x reference)
//
#include <hip/hip_runtime.h>

// SpringMass RK4 scan. State s=(v,x), sdot = L s + g, L=[[-C,-k],[1,0]], g=(F,0).
// RK4 for constant-coefficient linear ODE is exactly:
//   s' = R s + r,  R = I + hL + h^2L^2/2 + h^3L^3/6 + h^4L^4/24
//                  r = (hI + h^2L/2 + h^3L^2/6 + h^4L^3/24) g
// Cayley-Hamilton: L^2 = aL - kI (a=-C) => R = P(k) I + Q(k) L, with
//   Q(k) = cQ0 + cQ1*k   (linear),  P(k) = 1 + cP1*k + cP2*k^2 (quadratic)
//   S = hI + ... = Ps(k) I + Qs(k) L, both linear in k; r = F*(Ps + a*Qs, Qs).
// Affine maps compose associatively -> parallel scan over time.

#define TPB 256
#define STEPS 16           // timesteps per thread; TPB*STEPS == T == 4096
#define NWAVE (TPB / 64)

constexpr double dh = 0.01;   // DT
constexpr double dA = -0.1;   // a = -C/M (C=0.1, M=1)

constexpr float DTF = (float)dh;
constexpr float AF  = (float)dA;

constexpr float cQ0 = (float)(dh + dA*dh*dh/2.0 + dA*dA*dh*dh*dh/6.0 + dA*dA*dA*dh*dh*dh*dh/24.0);
constexpr float cQ1 = (float)(-(dh*dh*dh/6.0 + dA*dh*dh*dh*dh/12.0));
constexpr float cP1 = (float)(-(dh*dh/2.0 + dA*dh*dh*dh/6.0 + dA*dA*dh*dh*dh*dh/24.0));
constexpr float cP2 = (float)(dh*dh*dh*dh/24.0);
constexpr float cS0 = (float)(dh*dh/2.0 + dA*dh*dh*dh/6.0 + dA*dA*dh*dh*dh*dh/24.0);
constexpr float cS1 = (float)(-dh*dh*dh*dh/24.0);
constexpr float cT1 = (float)(-(dh*dh*dh/6.0 + dA*dh*dh*dh*dh/24.0));

struct Xf { float a11, a12, a21, a22, bv, bx; };   // s -> A s + b

struct StepRR { float R11, R12, R21, R22, rv, rx; };

__device__ __forceinline__ StepRR makeStep(float k, float F) {
    StepRR s;
    float Q  = fmaf(cQ1, k, cQ0);
    float P  = fmaf(fmaf(cP2, k, cP1), k, 1.0f);
    s.R11 = fmaf(AF, Q, P);      // P + a*Q
    s.R12 = -k * Q;
    s.R21 = Q;
    s.R22 = P;
    float Qs = fmaf(cS1, k, cS0);
    float Ps = fmaf(cT1, k, DTF);
    s.rv = F * fmaf(AF, Qs, Ps); // F*(Ps + a*Qs)
    s.rx = F * Qs;
    return s;
}

// combine: apply e (earlier) then l (later): A = Al*Ae, b = Al*be + bl
__device__ __forceinline__ Xf combine(const Xf& e, const Xf& l) {
    Xf r;
    r.a11 = fmaf(l.a11, e.a11, l.a12 * e.a21);
    r.a12 = fmaf(l.a11, e.a12, l.a12 * e.a22);
    r.a21 = fmaf(l.a21, e.a11, l.a22 * e.a21);
    r.a22 = fmaf(l.a21, e.a12, l.a22 * e.a22);
    r.bv  = fmaf(l.a11, e.bv, fmaf(l.a12, e.bx, l.bv));
    r.bx  = fmaf(l.a21, e.bv, fmaf(l.a22, e.bx, l.bx));
    return r;
}

// fold one more step (later) onto accumulated transform t (earlier)
__device__ __forceinline__ void foldStep(Xf& t, float k, float F) {
    StepRR s = makeStep(k, F);
    float a11 = fmaf(s.R11, t.a11, s.R12 * t.a21);
    float a12 = fmaf(s.R11, t.a12, s.R12 * t.a22);
    float a21 = fmaf(s.R21, t.a11, s.R22 * t.a21);
    float a22 = fmaf(s.R21, t.a12, s.R22 * t.a22);
    float bv  = fmaf(s.R11, t.bv, fmaf(s.R12, t.bx, s.rv));
    float bx  = fmaf(s.R21, t.bv, fmaf(s.R22, t.bx, s.rx));
    t.a11 = a11; t.a12 = a12; t.a21 = a21; t.a22 = a22; t.bv = bv; t.bx = bx;
}

// advance state one step, return xddot after the update
__device__ __forceinline__ float stepState(float& v, float& x, float k, float F) {
    StepRR s = makeStep(k, F);
    float vn = fmaf(s.R11, v, fmaf(s.R12, x, s.rv));
    float xn = fmaf(s.R21, v, fmaf(s.R22, x, s.rx));
    v = vn; x = xn;
    return fmaf(AF, vn, fmaf(-k, xn, F));   // -C*v' - k*x' + F
}

__device__ __forceinline__ Xf shflUp(const Xf& t, int d) {
    Xf r;
    r.a11 = __shfl_up(t.a11, d);
    r.a12 = __shfl_up(t.a12, d);
    r.a21 = __shfl_up(t.a21, d);
    r.a22 = __shfl_up(t.a22, d);
    r.bv  = __shfl_up(t.bv, d);
    r.bx  = __shfl_up(t.bx, d);
    return r;
}

__global__ __launch_bounds__(TPB) void spring_scan_kernel(
    const float* __restrict__ in, const float* __restrict__ v0g,
    const float* __restrict__ x0g, float* __restrict__ out, int T) {
    const int b    = blockIdx.x;
    const int j    = threadIdx.x;
    const int lane = j & 63;
    const int wave = j >> 6;

    // ---- load 16 (k,F) pairs as 8 float4, keep in registers ----
    const float4* in4 = (const float4*)(in + (size_t)b * (size_t)T * 2);
    float4 kf[STEPS / 2];
#pragma unroll
    for (int i = 0; i < STEPS / 2; ++i) kf[i] = in4[(size_t)j * (STEPS / 2) + i];

    // ---- pass 1: compose this thread's 16-step affine transform ----
    Xf t = {1.f, 0.f, 0.f, 1.f, 0.f, 0.f};
#pragma unroll
    for (int i = 0; i < STEPS / 2; ++i) {
        foldStep(t, kf[i].x, kf[i].y);
        foldStep(t, kf[i].z, kf[i].w);
    }

    // ---- wave-level inclusive Kogge-Stone scan ----
#pragma unroll
    for (int d = 1; d < 64; d <<= 1) {
        Xf o = shflUp(t, d);
        if (lane >= d) t = combine(o, t);
    }

    // ---- block-level: scan the NWAVE wave totals via LDS ----
    __shared__ Xf wtot[NWAVE];
    if (lane == 63) wtot[wave] = t;
    Xf ex = shflUp(t, 1);        // exclusive within wave (lane 0: garbage)
    __syncthreads();
    Xf pre = {1.f, 0.f, 0.f, 1.f, 0.f, 0.f};
#pragma unroll
    for (int w = 0; w < NWAVE - 1; ++w) {
        if (w < wave) pre = combine(pre, wtot[w]);
    }
    Xf myex = (lane == 0) ? pre : combine(pre, ex);

    // ---- state at this thread's chunk start ----
    float v0 = v0g[b], x0 = x0g[b];
    float v = fmaf(myex.a11, v0, fmaf(myex.a12, x0, myex.bv));
    float x = fmaf(myex.a21, v0, fmaf(myex.a22, x0, myex.bx));

    // ---- pass 2: re-run 16 steps from registers, emit xddot ----
    float4 ov[STEPS / 4];
    float* op = (float*)ov;
#pragma unroll
    for (int i = 0; i < STEPS / 2; ++i) {
        op[2 * i]     = stepState(v, x, kf[i].x, kf[i].y);
        op[2 * i + 1] = stepState(v, x, kf[i].z, kf[i].w);
    }
    float4* out4 = (float4*)(out + (size_t)b * (size_t)T);
#pragma unroll
    for (int i = 0; i < STEPS / 4; ++i) out4[(size_t)j * (STEPS / 4) + i] = ov[i];
}

// Fallback for unexpected shapes: one thread per trajectory, reference arithmetic.
__global__ void spring_naive_kernel(const float* __restrict__ in,
                                    const float* __restrict__ v0g,
                                    const float* __restrict__ x0g,
                                    float* __restrict__ out, int B, int T) {
    int b = blockIdx.x * blockDim.x + threadIdx.x;
    if (b >= B) return;
    const float dt = 0.01f, half = 0.005f, C = 0.1f;
    float v = v0g[b], x = x0g[b];
    const float* p = in + (size_t)b * (size_t)T * 2;
    float* o = out + (size_t)b * (size_t)T;
    for (int tt = 0; tt < T; ++tt) {
        float k = p[2 * tt], F = p[2 * tt + 1];
        float a1 = F - C * v - k * x;                   float s1 = v;
        float v2 = v + half * a1, x2 = x + half * s1;
        float a2 = F - C * v2 - k * x2;                 float s2 = v2;
        float v3 = v + half * a2, x3 = x + half * s2;
        float a3 = F - C * v3 - k * x3;                 float s3 = v3;
        float v4 = v + dt * a3,  x4 = x + dt * s3;
        float a4 = F - C * v4 - k * x4;                 float s4 = v4;
        v = v + dt / 6.f * (a1 + 2.f * a2 + 2.f * a3 + a4);
        x = x + dt / 6.f * (s1 + 2.f * s2 + 2.f * s3 + s4);
        o[tt] = F - C * v - k * x;
    }
}

extern "C" void kernel_launch(void* const* d_in, const int* in_sizes, int n_in,
                              void* d_out, int out_size, void* d_ws, size_t ws_size,
                              hipStream_t stream) {
    const float* in  = (const float*)d_in[0];
    const float* v0g = (const float*)d_in[1];
    const float* x0g = (const float*)d_in[2];
    float* out = (float*)d_out;

    const int B = in_sizes[1];                 // 4096
    const int T = in_sizes[0] / (2 * B);       // 4096

    if (T == TPB * STEPS) {
        spring_scan_kernel<<<B, TPB, 0, stream>>>(in, v0g, x0g, out, T);
    } else {
        int tpb = 256;
        spring_naive_kernel<<<(B + tpb - 1) / tpb, tpb, 0, stream>>>(in, v0g, x0g, out, B, T);
    }
}

// Round 2
// 212.151 us; speedup vs baseline: 1.0133x; 1.0133x over previous
//
#include <hip/hip_runtime.h>

// SpringMass RK4 scan. State s=(v,x), sdot = L s + g, L=[[-C,-k],[1,0]], g=(F,0).
// RK4 for constant-coefficient linear ODE is exactly an affine map s' = R s + r
// with (Cayley-Hamilton) R = P(k) I + Q(k) L, P quadratic / Q linear in k.
// Affine maps compose associatively -> parallel scan over time.
//
// R2: all global access coalesced via LDS staging (padded layout L(d)=d+2*(d>>5),
// conflict-free for b64 at the 4-lane/pair-bank structural floor); no register
// arrays live across the shuffle scan (R1 held 32+ VGPRs of kf[]/ov[] across it —
// suspected spills / L1 scatter thrash caused the 7x-off-floor 215us).

#define TPB 256
#define STEPS 16           // timesteps per thread; TPB*STEPS == T == 4096
#define NWAVE (TPB / 64)

constexpr double dh = 0.01;   // DT
constexpr double dA = -0.1;   // a = -C/M (C=0.1, M=1)

constexpr float DTF = (float)dh;
constexpr float AF  = (float)dA;

constexpr float cQ0 = (float)(dh + dA*dh*dh/2.0 + dA*dA*dh*dh*dh/6.0 + dA*dA*dA*dh*dh*dh*dh/24.0);
constexpr float cQ1 = (float)(-(dh*dh*dh/6.0 + dA*dh*dh*dh*dh/12.0));
constexpr float cP1 = (float)(-(dh*dh/2.0 + dA*dh*dh*dh/6.0 + dA*dA*dh*dh*dh*dh/24.0));
constexpr float cP2 = (float)(dh*dh*dh*dh/24.0);
constexpr float cS0 = (float)(dh*dh/2.0 + dA*dh*dh*dh/6.0 + dA*dA*dh*dh*dh*dh/24.0);
constexpr float cS1 = (float)(-dh*dh*dh*dh/24.0);
constexpr float cT1 = (float)(-(dh*dh*dh/6.0 + dA*dh*dh*dh*dh/24.0));

struct Xf { float a11, a12, a21, a22, bv, bx; };   // s -> A s + b
struct StepRR { float R11, R12, R21, R22, rv, rx; };

__device__ __forceinline__ StepRR makeStep(float k, float F) {
    StepRR s;
    float Q  = fmaf(cQ1, k, cQ0);
    float P  = fmaf(fmaf(cP2, k, cP1), k, 1.0f);
    s.R11 = fmaf(AF, Q, P);      // P + a*Q
    s.R12 = -k * Q;
    s.R21 = Q;
    s.R22 = P;
    float Qs = fmaf(cS1, k, cS0);
    float Ps = fmaf(cT1, k, DTF);
    s.rv = F * fmaf(AF, Qs, Ps); // F*(Ps + a*Qs)
    s.rx = F * Qs;
    return s;
}

// combine: apply e (earlier) then l (later): A = Al*Ae, b = Al*be + bl
__device__ __forceinline__ Xf combine(const Xf& e, const Xf& l) {
    Xf r;
    r.a11 = fmaf(l.a11, e.a11, l.a12 * e.a21);
    r.a12 = fmaf(l.a11, e.a12, l.a12 * e.a22);
    r.a21 = fmaf(l.a21, e.a11, l.a22 * e.a21);
    r.a22 = fmaf(l.a21, e.a12, l.a22 * e.a22);
    r.bv  = fmaf(l.a11, e.bv, fmaf(l.a12, e.bx, l.bv));
    r.bx  = fmaf(l.a21, e.bv, fmaf(l.a22, e.bx, l.bx));
    return r;
}

__device__ __forceinline__ void foldStep(Xf& t, float k, float F) {
    StepRR s = makeStep(k, F);
    float a11 = fmaf(s.R11, t.a11, s.R12 * t.a21);
    float a12 = fmaf(s.R11, t.a12, s.R12 * t.a22);
    float a21 = fmaf(s.R21, t.a11, s.R22 * t.a21);
    float a22 = fmaf(s.R21, t.a12, s.R22 * t.a22);
    float bv  = fmaf(s.R11, t.bv, fmaf(s.R12, t.bx, s.rv));
    float bx  = fmaf(s.R21, t.bv, fmaf(s.R22, t.bx, s.rx));
    t.a11 = a11; t.a12 = a12; t.a21 = a21; t.a22 = a22; t.bv = bv; t.bx = bx;
}

__device__ __forceinline__ float stepState(float& v, float& x, float k, float F) {
    StepRR s = makeStep(k, F);
    float vn = fmaf(s.R11, v, fmaf(s.R12, x, s.rv));
    float xn = fmaf(s.R21, v, fmaf(s.R22, x, s.rx));
    v = vn; x = xn;
    return fmaf(AF, vn, fmaf(-k, xn, F));   // -C*v' - k*x' + F
}

__device__ __forceinline__ Xf shflUp(const Xf& t, int d) {
    Xf r;
    r.a11 = __shfl_up(t.a11, d);
    r.a12 = __shfl_up(t.a12, d);
    r.a21 = __shfl_up(t.a21, d);
    r.a22 = __shfl_up(t.a22, d);
    r.bv  = __shfl_up(t.bv, d);
    r.bx  = __shfl_up(t.bx, d);
    return r;
}

// Padded LDS index: one block's input is 8192 dwords; insert 2 pad dwords per 32.
// L(d) = d + 2*(d>>5). Verified bank math:
//  - stage writes (b64 pairs of a coalesced float4): 4 lanes/pair-bank = floor, free
//  - per-thread pair reads (b64 at L=34*tid+2m): (tid+m)%16 pair-bank, 4 lanes = floor
//  - xddot gather (b32): 4-way (1.58x) on 16 reads — acceptable
__global__ __launch_bounds__(TPB) void spring_scan_kernel(
    const float* __restrict__ in, const float* __restrict__ v0g,
    const float* __restrict__ x0g, float* __restrict__ out, int T) {
    const int b    = blockIdx.x;
    const int tid  = threadIdx.x;
    const int lane = tid & 63;
    const int wave = tid >> 6;

    __shared__ float lds[8704];      // 8192 + 512 pad dwords = 34816 B
    __shared__ Xf wtot[NWAVE];

    // ---- stage: coalesced global float4 -> padded LDS ----
    const float4* in4 = (const float4*)(in + (size_t)b * (size_t)T * 2);
#pragma unroll
    for (int it = 0; it < 8; ++it) {
        int e4 = tid + TPB * it;             // float4 index within block row
        float4 vv = in4[e4];
        int L = 4 * e4 + 2 * (e4 >> 3);      // = PD(4*e4)
        *(float2*)&lds[L]     = make_float2(vv.x, vv.y);
        *(float2*)&lds[L + 2] = make_float2(vv.z, vv.w);
    }
    __syncthreads();

    // ---- pass 1: compose this thread's 16-step affine transform from LDS ----
    const int base = 34 * tid;               // PD(2*(16*tid))
    Xf t = {1.f, 0.f, 0.f, 1.f, 0.f, 0.f};
#pragma unroll
    for (int m = 0; m < STEPS; ++m) {
        float2 kf = *(const float2*)&lds[base + 2 * m];
        foldStep(t, kf.x, kf.y);
    }

    // ---- wave-level inclusive Kogge-Stone scan ----
#pragma unroll
    for (int d = 1; d < 64; d <<= 1) {
        Xf o = shflUp(t, d);
        if (lane >= d) t = combine(o, t);
    }

    // ---- block-level: scan the NWAVE wave totals ----
    if (lane == 63) wtot[wave] = t;
    Xf ex = shflUp(t, 1);        // exclusive within wave (lane 0: garbage)
    __syncthreads();
    Xf pre = {1.f, 0.f, 0.f, 1.f, 0.f, 0.f};
#pragma unroll
    for (int w = 0; w < NWAVE - 1; ++w) {
        if (w < wave) pre = combine(pre, wtot[w]);
    }
    Xf myex = (lane == 0) ? pre : combine(pre, ex);

    // ---- state at this thread's chunk start ----
    float v0 = v0g[b], x0 = x0g[b];
    float v = fmaf(myex.a11, v0, fmaf(myex.a12, x0, myex.bv));
    float x = fmaf(myex.a21, v0, fmaf(myex.a22, x0, myex.bx));

    // ---- pass 2: re-run 16 steps from LDS, write xddot back in-place ----
#pragma unroll
    for (int m = 0; m < STEPS; ++m) {
        float2 kf = *(const float2*)&lds[base + 2 * m];
        float xdd = stepState(v, x, kf.x, kf.y);
        lds[base + 2 * m] = xdd;             // overwrite k-slot (only owner reads it)
    }
    __syncthreads();

    // ---- gather from LDS, coalesced float4 store ----
    float4* out4 = (float4*)(out + (size_t)b * (size_t)T);
#pragma unroll
    for (int i = 0; i < 4; ++i) {
        int e0 = 4 * tid + 1024 * i;         // first of 4 consecutive xddot indices
        int Lb = 34 * (e0 >> 4) + 2 * (e0 & 15);   // same owner-thread for all 4
        float4 o;
        o.x = lds[Lb];
        o.y = lds[Lb + 2];
        o.z = lds[Lb + 4];
        o.w = lds[Lb + 6];
        out4[tid + TPB * i] = o;
    }
}

// Fallback for unexpected shapes: one thread per trajectory, reference arithmetic.
__global__ void spring_naive_kernel(const float* __restrict__ in,
                                    const float* __restrict__ v0g,
                                    const float* __restrict__ x0g,
                                    float* __restrict__ out, int B, int T) {
    int b = blockIdx.x * blockDim.x + threadIdx.x;
    if (b >= B) return;
    const float dt = 0.01f, half = 0.005f, C = 0.1f;
    float v = v0g[b], x = x0g[b];
    const float* p = in + (size_t)b * (size_t)T * 2;
    float* o = out + (size_t)b * (size_t)T;
    for (int tt = 0; tt < T; ++tt) {
        float k = p[2 * tt], F = p[2 * tt + 1];
        float a1 = F - C * v - k * x;                   float s1 = v;
        float v2 = v + half * a1, x2 = x + half * s1;
        float a2 = F - C * v2 - k * x2;                 float s2 = v2;
        float v3 = v + half * a2, x3 = x + half * s2;
        float a3 = F - C * v3 - k * x3;                 float s3 = v3;
        float v4 = v + dt * a3,  x4 = x + dt * s3;
        float a4 = F - C * v4 - k * x4;                 float s4 = v4;
        v = v + dt / 6.f * (a1 + 2.f * a2 + 2.f * a3 + a4);
        x = x + dt / 6.f * (s1 + 2.f * s2 + 2.f * s3 + s4);
        o[tt] = F - C * v - k * x;
    }
}

extern "C" void kernel_launch(void* const* d_in, const int* in_sizes, int n_in,
                              void* d_out, int out_size, void* d_ws, size_t ws_size,
                              hipStream_t stream) {
    const float* in  = (const float*)d_in[0];
    const float* v0g = (const float*)d_in[1];
    const float* x0g = (const float*)d_in[2];
    float* out = (float*)d_out;

    const int B = in_sizes[1];                 // 4096
    const int T = in_sizes[0] / (2 * B);       // 4096

    if (T == TPB * STEPS) {
        spring_scan_kernel<<<B, TPB, 0, stream>>>(in, v0g, x0g, out, T);
    } else {
        int tpb = 256;
        spring_naive_kernel<<<(B + tpb - 1) / tpb, tpb, 0, stream>>>(in, v0g, x0g, out, B, T);
    }
}